// Round 2
// baseline (363.150 us; speedup 1.0000x reference)
//
#include <hip/hip_runtime.h>

// DeltaDequantization: B=1024, T=2048, NB=32, ADAPT_STEP=32, nchunks=64.
// Key simplification: per-chunk bin rescale is a SCALAR per batch, so
// bins[b,:] == quant_bins[:] * S_b  (running product of chunk scales).
// => out[b,t] = pred_c + S_c * db[t]  with db/dc simple dot-32s of x rows.

#define TLEN 2048
#define NB 32
#define NCHUNK 64   // TLEN / 32

__global__ __launch_bounds__(256, 4) void delta_dequant_kernel(
    const float* __restrict__ x,
    const float* __restrict__ quant_bins,
    const float* __restrict__ change_scales,
    float* __restrict__ out)
{
    __shared__ float s_db[TLEN];   // 8 KB: dot(x[t,:], quant_bins)
    __shared__ float s_dc[TLEN];   // 8 KB: dot(x[t,:], change_scales)
    __shared__ float s_S[NCHUNK];  // holds G_c, then S_c after scan
    __shared__ float s_P[NCHUNK];  // holds A_c, then pred_c after scan

    const int b    = blockIdx.x;
    const int tid  = threadIdx.x;
    const int lane = tid & 63;
    const int wid  = tid >> 6;     // wave id 0..3
    const int sub  = lane & 7;     // which float4 of the 32-float row
    const int tg   = lane >> 3;    // timestep within the wave's group of 8

    // Each lane needs only its 4 of the 32 bin/scale values.
    const float4 qb4 = ((const float4*)quant_bins)[sub];
    const float4 cs4 = ((const float4*)change_scales)[sub];

    const float* __restrict__ xb = x + (size_t)b * (TLEN * NB);

    // ---- Phase 1: db/dc for all 2048 timesteps ----
    // Wave reads 8 timesteps (1 KB contiguous) per iteration: lane i covers
    // t = base + (i>>3), floats 4*(i&7) .. 4*(i&7)+3  -> perfectly coalesced.
    for (int k = 0; k < TLEN / 32; ++k) {            // 64 iterations
        int t = ((k * 4 + wid) << 3) + tg;
        float4 v = ((const float4*)(xb + t * NB))[sub];
        float db = v.x * qb4.x + v.y * qb4.y + v.z * qb4.z + v.w * qb4.w;
        float dc = v.x * cs4.x + v.y * cs4.y + v.z * cs4.z + v.w * cs4.w;
        // reduce across the 8-lane sub group (xor stays inside the group)
        db += __shfl_xor(db, 1); dc += __shfl_xor(dc, 1);
        db += __shfl_xor(db, 2); dc += __shfl_xor(dc, 2);
        db += __shfl_xor(db, 4); dc += __shfl_xor(dc, 4);
        if (sub == 0) { s_db[t] = db; s_dc[t] = dc; }
    }
    __syncthreads();

    // ---- Phase 2a: per-chunk means (A_c = mean db, G_c = mean dc) ----
    // Each thread sums 8 consecutive timesteps; 4 threads cover one chunk.
    float pa = 0.f, pg = 0.f;
    #pragma unroll
    for (int j = 0; j < 8; ++j) {
        pa += s_db[tid * 8 + j];
        pg += s_dc[tid * 8 + j];
    }
    pa += __shfl_xor(pa, 1); pg += __shfl_xor(pg, 1);
    pa += __shfl_xor(pa, 2); pg += __shfl_xor(pg, 2);
    if ((tid & 3) == 0) {
        s_P[tid >> 2] = pa * (1.0f / 32.0f);   // A_c
        s_S[tid >> 2] = pg * (1.0f / 32.0f);   // G_c
    }
    __syncthreads();

    // ---- Phase 2b: serial 64-step scalar scan (tiny) ----
    if (tid == 0) {
        float S = 1.0f, pred = 0.0f;
        for (int c = 0; c < NCHUNK; ++c) {
            float G = s_S[c], A = s_P[c];
            s_S[c] = S; s_P[c] = pred;         // exclusive-scan values
            pred += S * A;
            S *= G;
        }
    }
    __syncthreads();

    // ---- Phase 3: out[b,t] = pred_c + S_c * db[t], coalesced float4 stores ----
    float* __restrict__ ob = out + (size_t)b * TLEN;
    #pragma unroll
    for (int i = 0; i < 2; ++i) {
        int t4 = tid + i * 256;                // float4 index, t = 4*t4
        int c  = t4 >> 3;                      // chunk = (4*t4)/32
        float S = s_S[c], P = s_P[c];
        float4 d4 = ((const float4*)s_db)[t4];
        float4 o;
        o.x = P + S * d4.x;
        o.y = P + S * d4.y;
        o.z = P + S * d4.z;
        o.w = P + S * d4.w;
        ((float4*)ob)[t4] = o;
    }
}

extern "C" void kernel_launch(void* const* d_in, const int* in_sizes, int n_in,
                              void* d_out, int out_size, void* d_ws, size_t ws_size,
                              hipStream_t stream) {
    const float* x  = (const float*)d_in[0];
    const float* qb = (const float*)d_in[1];
    const float* cs = (const float*)d_in[2];
    float* out = (float*)d_out;
    int B = out_size / TLEN;   // 1024
    delta_dequant_kernel<<<B, 256, 0, stream>>>(x, qb, cs, out);
}

// Round 4
// 361.125 us; speedup vs baseline: 1.0056x; 1.0056x over previous
//
#include <hip/hip_runtime.h>

// DeltaDequantization: B=1024, T=2048, NB=32, ADAPT_STEP=32, nchunks=64.
// Algebraic collapse: the per-chunk bin rescale is a SCALAR per batch
// (scale = mean_s dot(x[s,:], change_scales)), so bins[b,:] = quant_bins * S_b.
// => out[b,t] = pred_c + S_c * db[t], db/dc = dot-32s of x rows, plus a
//    trivial 64-step scalar scan per batch.

#define TLEN 2048
#define NB 32
#define NCHUNK 64   // TLEN / 32

__global__ __launch_bounds__(512, 8) void delta_dequant_kernel(
    const float* __restrict__ x,
    const float* __restrict__ quant_bins,
    const float* __restrict__ change_scales,
    float* __restrict__ out)
{
    __shared__ float s_db[TLEN];   // 8 KB: dot(x[t,:], quant_bins)
    __shared__ float s_dc[TLEN];   // 8 KB: dot(x[t,:], change_scales)
    __shared__ float s_S[NCHUNK];  // G_c, then exclusive-scanned S_c
    __shared__ float s_P[NCHUNK];  // A_c, then exclusive-scanned pred_c

    const int b    = blockIdx.x;
    const int tid  = threadIdx.x;
    const int lane = tid & 63;
    const int wid  = tid >> 6;     // wave id 0..7
    const int sub  = lane & 7;     // which float4 of the 32-float row
    const int tg   = lane >> 3;    // timestep within the wave's group of 8

    // Each lane needs only its 4 of the 32 bin/scale values.
    const float4 qb4 = ((const float4*)quant_bins)[sub];
    const float4 cs4 = ((const float4*)change_scales)[sub];

    const float* __restrict__ xb = x + (size_t)b * (TLEN * NB);

    // ---- Phase 1: db/dc for all 2048 timesteps ----
    // 8 waves x 8 rows = 64 rows per k-iteration; 32 iterations.
    // Batch 4 loads (4 KB in flight per wave) before the dependent
    // shfl-reduce chains so HBM latency is covered by ILP as well as TLP.
    for (int k = 0; k < 32; k += 4) {
        const int tbase = k * 64 + wid * 8 + tg;
        float4 v[4];
        #pragma unroll
        for (int u = 0; u < 4; ++u)
            v[u] = ((const float4*)(xb + (size_t)(tbase + u * 64) * NB))[sub];
        #pragma unroll
        for (int u = 0; u < 4; ++u) {
            float db = v[u].x * qb4.x + v[u].y * qb4.y + v[u].z * qb4.z + v[u].w * qb4.w;
            float dc = v[u].x * cs4.x + v[u].y * cs4.y + v[u].z * cs4.z + v[u].w * cs4.w;
            db += __shfl_xor(db, 1); dc += __shfl_xor(dc, 1);
            db += __shfl_xor(db, 2); dc += __shfl_xor(dc, 2);
            db += __shfl_xor(db, 4); dc += __shfl_xor(dc, 4);
            if (sub == 0) { s_db[tbase + u * 64] = db; s_dc[tbase + u * 64] = dc; }
        }
    }
    __syncthreads();

    // ---- Phase 2a: per-chunk means (A_c = mean db, G_c = mean dc) ----
    // 512 threads x 1 float4 covers all 2048 values; 8 threads per chunk.
    {
        float4 a4 = ((const float4*)s_db)[tid];
        float4 g4 = ((const float4*)s_dc)[tid];
        float pa = a4.x + a4.y + a4.z + a4.w;
        float pg = g4.x + g4.y + g4.z + g4.w;
        pa += __shfl_xor(pa, 1); pg += __shfl_xor(pg, 1);
        pa += __shfl_xor(pa, 2); pg += __shfl_xor(pg, 2);
        pa += __shfl_xor(pa, 4); pg += __shfl_xor(pg, 4);
        if ((tid & 7) == 0) {
            s_P[tid >> 3] = pa * (1.0f / 32.0f);   // A_c
            s_S[tid >> 3] = pg * (1.0f / 32.0f);   // G_c
        }
    }
    __syncthreads();

    // ---- Phase 2b: serial 64-step scalar scan (tiny) ----
    if (tid == 0) {
        float S = 1.0f, pred = 0.0f;
        for (int c = 0; c < NCHUNK; ++c) {
            float G = s_S[c], A = s_P[c];
            s_S[c] = S; s_P[c] = pred;             // exclusive-scan values
            pred += S * A;
            S *= G;
        }
    }
    __syncthreads();

    // ---- Phase 3: out[b,t] = pred_c + S_c * db[t], one float4 per thread ----
    {
        float* __restrict__ ob = out + (size_t)b * TLEN;
        const int c = tid >> 3;                    // (4*tid)/32
        const float S = s_S[c], P = s_P[c];
        float4 d4 = ((const float4*)s_db)[tid];
        float4 o;
        o.x = P + S * d4.x;
        o.y = P + S * d4.y;
        o.z = P + S * d4.z;
        o.w = P + S * d4.w;
        ((float4*)ob)[tid] = o;
    }
}

extern "C" void kernel_launch(void* const* d_in, const int* in_sizes, int n_in,
                              void* d_out, int out_size, void* d_ws, size_t ws_size,
                              hipStream_t stream) {
    const float* x  = (const float*)d_in[0];
    const float* qb = (const float*)d_in[1];
    const float* cs = (const float*)d_in[2];
    float* out = (float*)d_out;
    int B = out_size / TLEN;   // 1024
    delta_dequant_kernel<<<B, 512, 0, stream>>>(x, qb, cs, out);
}